// Round 1
// baseline (759.089 us; speedup 1.0000x reference)
//
#include <hip/hip_runtime.h>
#include <hip/hip_bf16.h>

typedef unsigned short u16;
typedef unsigned int u32;

#define T_TOK 16384
#define DIM   1024
#define NEXP  8

// ---------- workspace layout (bytes) ----------
// xb     : T*D*2      = 33,554,432   (x in bf16)
// wb     : E*D*D*2    = 16,777,216   (expert_w in bf16)
// counts : 8*4 (pad 64)
// lists  : E*T*4      = 524,288      (token index per expert slot)
// wlists : E*T*4      = 524,288      (gate weight per expert slot)
// total ~51.4 MB
#define XB_OFF     0
#define WB_OFF     33554432
#define CNT_OFF    50331648
#define LIST_OFF   50331712
#define WLIST_OFF  50856000

__device__ __forceinline__ u16 f2bf(float f) {
    u32 u = __float_as_uint(f);
    u += 0x7fff + ((u >> 16) & 1);   // round-to-nearest-even
    return (u16)(u >> 16);
}

__global__ __launch_bounds__(64) void k_zero(int* counts) {
    if (threadIdx.x < NEXP) counts[threadIdx.x] = 0;
}

__global__ __launch_bounds__(256) void k_cvt(const float* __restrict__ in,
                                             u16* __restrict__ out, int n4) {
    int i = blockIdx.x * 256 + threadIdx.x;
    if (i >= n4) return;
    float4 v = reinterpret_cast<const float4*>(in)[i];
    ushort4 u;
    u.x = f2bf(v.x); u.y = f2bf(v.y); u.z = f2bf(v.z); u.w = f2bf(v.w);
    reinterpret_cast<ushort4*>(out)[i] = u;
}

// one wave per token: router logits (fp32), top-2 weights, fused x->bf16 and
// bias-init of out, builds per-expert token lists.
__global__ __launch_bounds__(256) void k_router(
    const float* __restrict__ x, const float* __restrict__ gw,
    const float* __restrict__ gb, const float* __restrict__ eb,
    float* __restrict__ out, float* __restrict__ logits,
    u16* __restrict__ xb, int* __restrict__ counts,
    int* __restrict__ lists, float* __restrict__ wlists)
{
    const int lane = threadIdx.x & 63;
    const int w    = threadIdx.x >> 6;
    const int t    = blockIdx.x * 4 + w;

    const float* xr = x + (size_t)t * DIM;
    float4 xs[4];
#pragma unroll
    for (int j = 0; j < 4; ++j)
        xs[j] = *reinterpret_cast<const float4*>(xr + (j * 64 + lane) * 4);

    float acc[NEXP];
#pragma unroll
    for (int e = 0; e < NEXP; ++e) {
        const float* gr = gw + e * DIM;
        float s = 0.f;
#pragma unroll
        for (int j = 0; j < 4; ++j) {
            float4 g = *reinterpret_cast<const float4*>(gr + (j * 64 + lane) * 4);
            s += xs[j].x * g.x + xs[j].y * g.y + xs[j].z * g.z + xs[j].w * g.w;
        }
        acc[e] = s;
    }
#pragma unroll
    for (int e = 0; e < NEXP; ++e) {
        float s = acc[e];
#pragma unroll
        for (int off = 1; off < 64; off <<= 1) s += __shfl_xor(s, off);
        acc[e] = s + gb[e];
    }
    // top-2, ties -> lower index (matches jax.lax.top_k)
    int i0 = 0; float v0 = acc[0];
#pragma unroll
    for (int e = 1; e < NEXP; ++e) if (acc[e] > v0) { v0 = acc[e]; i0 = e; }
    int i1 = -1; float v1 = -3.4e38f;
#pragma unroll
    for (int e = 0; e < NEXP; ++e) if (e != i0 && acc[e] > v1) { v1 = acc[e]; i1 = e; }
    // renormalized top-2 weights == softmax over the two logits
    float e1  = __expf(v1 - v0);
    float inv = 1.f / (1.f + e1);
    float w0 = inv, w1 = e1 * inv;

    // fused: x -> bf16, out = w0*b[i0] + w1*b[i1]
    const float* b0 = eb + i0 * DIM;
    const float* b1 = eb + i1 * DIM;
    float* orow = out + (size_t)t * DIM;
    u16*   xrow = xb  + (size_t)t * DIM;
#pragma unroll
    for (int j = 0; j < 4; ++j) {
        int c = (j * 64 + lane) * 4;
        float4 v = xs[j];
        ushort4 u;
        u.x = f2bf(v.x); u.y = f2bf(v.y); u.z = f2bf(v.z); u.w = f2bf(v.w);
        *reinterpret_cast<ushort4*>(xrow + c) = u;
        float4 f0 = *reinterpret_cast<const float4*>(b0 + c);
        float4 f1 = *reinterpret_cast<const float4*>(b1 + c);
        float4 o;
        o.x = w0 * f0.x + w1 * f1.x;
        o.y = w0 * f0.y + w1 * f1.y;
        o.z = w0 * f0.z + w1 * f1.z;
        o.w = w0 * f0.w + w1 * f1.w;
        *reinterpret_cast<float4*>(orow + c) = o;
    }
    if (lane == 0) {
#pragma unroll
        for (int e = 0; e < NEXP; ++e) logits[(size_t)t * NEXP + e] = acc[e];
        int p0 = atomicAdd(&counts[i0], 1);
        lists[i0 * T_TOK + p0]  = t;
        wlists[i0 * T_TOK + p0] = w0;
        int p1 = atomicAdd(&counts[i1], 1);
        lists[i1 * T_TOK + p1]  = t;
        wlists[i1 * T_TOK + p1] = w1;
    }
}

// grouped GEMM: per (expert, m-tile, n-tile). C[slot][n] = sum_k x[tok[slot]][k]*W[e][n][k]
// 128x128 tile, BK=64, 4 waves (2x2), each wave 4x4 frags of 16x16x32 bf16 MFMA.
#define BM 128
#define BN 128
#define BK 64
#define MT (T_TOK / BM)   // 128
#define NT (DIM / BN)     // 8

typedef __attribute__((ext_vector_type(8))) short bf16x8;
typedef __attribute__((ext_vector_type(4))) float f32x4;

__global__ __launch_bounds__(256) void k_gemm(
    const u16* __restrict__ xb, const u16* __restrict__ wb,
    const int* __restrict__ counts, const int* __restrict__ lists,
    const float* __restrict__ wlists, float* __restrict__ out)
{
    const int bid = blockIdx.x;
    const int e   = bid >> 10;          // / (MT*NT)
    const int mt  = (bid >> 3) & 127;
    const int nt  = bid & 7;
    const int cnt = counts[e];
    if (mt * BM >= cnt) return;

    __shared__ u16 ldsA[BM * BK];
    __shared__ u16 ldsB[BN * BK];

    const int tid  = threadIdx.x;
    const int lane = tid & 63;
    const int wid  = tid >> 6;
    const int wr   = wid >> 1, wc = wid & 1;

    // staging map: inst i covers rows i*32 + (tid>>3), k-chunk (tid&7)*8 (8 bf16 = 16B)
    const int srow = tid >> 3;
    const int skc  = (tid & 7) * 8;
    const int listbase = e * T_TOK;

    int tokA[4];
#pragma unroll
    for (int i = 0; i < 4; ++i) {
        int slot = mt * BM + i * 32 + srow;
        int cl   = slot < cnt ? slot : cnt - 1;
        tokA[i]  = lists[listbase + cl];
    }
    const size_t wbase = (size_t)e * DIM * DIM + (size_t)(nt * BN) * DIM;

    f32x4 acc[4][4];
#pragma unroll
    for (int mi = 0; mi < 4; ++mi)
#pragma unroll
        for (int ni = 0; ni < 4; ++ni) acc[mi][ni] = (f32x4)0.f;

    for (int k0 = 0; k0 < DIM; k0 += BK) {
        uint4 ra[4], rb[4];
#pragma unroll
        for (int i = 0; i < 4; ++i) {
            ra[i] = *reinterpret_cast<const uint4*>(xb + (size_t)tokA[i] * DIM + k0 + skc);
            rb[i] = *reinterpret_cast<const uint4*>(wb + wbase + (size_t)(i * 32 + srow) * DIM + k0 + skc);
        }
        __syncthreads();
#pragma unroll
        for (int i = 0; i < 4; ++i) {
            *reinterpret_cast<uint4*>(ldsA + (i * 32 + srow) * BK + skc) = ra[i];
            *reinterpret_cast<uint4*>(ldsB + (i * 32 + srow) * BK + skc) = rb[i];
        }
        __syncthreads();
#pragma unroll
        for (int ks = 0; ks < 2; ++ks) {
            const int kof = ks * 32 + (lane >> 4) * 8;
            bf16x8 af[4], bfr[4];
#pragma unroll
            for (int mi = 0; mi < 4; ++mi)
                af[mi] = *reinterpret_cast<const bf16x8*>(ldsA + (wr * 64 + mi * 16 + (lane & 15)) * BK + kof);
#pragma unroll
            for (int ni = 0; ni < 4; ++ni)
                bfr[ni] = *reinterpret_cast<const bf16x8*>(ldsB + (wc * 64 + ni * 16 + (lane & 15)) * BK + kof);
#pragma unroll
            for (int mi = 0; mi < 4; ++mi)
#pragma unroll
                for (int ni = 0; ni < 4; ++ni)
                    acc[mi][ni] = __builtin_amdgcn_mfma_f32_16x16x32_bf16(af[mi], bfr[ni], acc[mi][ni], 0, 0, 0);
        }
    }

    // epilogue: C/D layout col=lane&15, row=(lane>>4)*4+reg  [m89-verified]
    const int rbase = (lane >> 4) * 4;
    const int cbase = nt * BN + wc * 64 + (lane & 15);
#pragma unroll
    for (int mi = 0; mi < 4; ++mi) {
#pragma unroll
        for (int r = 0; r < 4; ++r) {
            int slot = mt * BM + wr * 64 + mi * 16 + rbase + r;
            if (slot < cnt) {
                int   tok = lists[listbase + slot];
                float wgt = wlists[listbase + slot];
                float* orow = out + (size_t)tok * DIM + cbase;
#pragma unroll
                for (int ni = 0; ni < 4; ++ni)
                    atomicAdd(orow + ni * 16, acc[mi][ni][r] * wgt);
            }
        }
    }
}

extern "C" void kernel_launch(void* const* d_in, const int* in_sizes, int n_in,
                              void* d_out, int out_size, void* d_ws, size_t ws_size,
                              hipStream_t stream) {
    const float* x  = (const float*)d_in[0];
    const float* gw = (const float*)d_in[1];
    const float* gb = (const float*)d_in[2];
    const float* ew = (const float*)d_in[3];
    const float* eb = (const float*)d_in[4];

    float* out    = (float*)d_out;
    float* logits = out + (size_t)T_TOK * DIM;

    char* ws      = (char*)d_ws;
    u16*  xb      = (u16*)(ws + XB_OFF);
    u16*  wb      = (u16*)(ws + WB_OFF);
    int*  counts  = (int*)(ws + CNT_OFF);
    int*  lists   = (int*)(ws + LIST_OFF);
    float* wlists = (float*)(ws + WLIST_OFF);

    k_zero<<<1, 64, 0, stream>>>(counts);
    k_cvt<<<(NEXP * DIM * DIM / 4 + 255) / 256, 256, 0, stream>>>(ew, wb, NEXP * DIM * DIM / 4);
    k_router<<<T_TOK / 4, 256, 0, stream>>>(x, gw, gb, eb, out, logits, xb, counts, lists, wlists);
    k_gemm<<<NEXP * MT * NT, 256, 0, stream>>>(xb, wb, counts, lists, wlists, out);
}

// Round 2
// 214.436 us; speedup vs baseline: 3.5399x; 3.5399x over previous
//
#include <hip/hip_runtime.h>
#include <hip/hip_bf16.h>

typedef unsigned short u16;
typedef unsigned int u32;

#define T_TOK 16384
#define DIM   1024
#define NEXP  8

// ---------- workspace layout (bytes) ----------
// xb     : T*D*2      = 33,554,432   (x in bf16)
// wb     : E*D*D*2    = 16,777,216   (expert_w in bf16)
// counts : 8 ints padded to 64B stride each = 512 B
// lists  : E*T*4      = 524,288
// wlists : E*T*4      = 524,288
#define XB_OFF     0
#define WB_OFF     33554432
#define CNT_OFF    50331648
#define LIST_OFF   50332160
#define WLIST_OFF  50856448

__device__ __forceinline__ u16 f2bf(float f) {
    u32 u = __float_as_uint(f);
    u += 0x7fff + ((u >> 16) & 1);   // round-to-nearest-even
    return (u16)(u >> 16);
}

__global__ __launch_bounds__(128) void k_zero(int* counts) {
    if (threadIdx.x < NEXP * 16) counts[threadIdx.x] = 0;
}

__global__ __launch_bounds__(256) void k_cvt(const float* __restrict__ in,
                                             u16* __restrict__ out, int n4) {
    int i = blockIdx.x * 256 + threadIdx.x;
    if (i >= n4) return;
    float4 v = reinterpret_cast<const float4*>(in)[i];
    ushort4 u;
    u.x = f2bf(v.x); u.y = f2bf(v.y); u.z = f2bf(v.z); u.w = f2bf(v.w);
    reinterpret_cast<ushort4*>(out)[i] = u;
}

// Router v2: 32 tokens/block (4 waves x 8 tokens). Per-token: wave-wide dot
// with 8 gate rows, shfl reduce, top-2, fused x->bf16 + bias-init of out.
// Bookkeeping: LDS histogram + LDS-atomic ranks, ONE global atomic per
// expert per block on 64B-padded counters (kills same-line serialization).
#define RT_PB 32

__global__ __launch_bounds__(256) void k_router(
    const float* __restrict__ x, const float* __restrict__ gw,
    const float* __restrict__ gb, const float* __restrict__ eb,
    float* __restrict__ out, float* __restrict__ logits,
    u16* __restrict__ xb, int* __restrict__ counts,
    int* __restrict__ lists, float* __restrict__ wlists)
{
    const int tid  = threadIdx.x;
    const int lane = tid & 63;
    const int w    = tid >> 6;

    __shared__ int   s_sel0[RT_PB], s_sel1[RT_PB];
    __shared__ float s_w0[RT_PB],  s_w1[RT_PB];
    __shared__ int   s_lcnt[NEXP], s_gbase[NEXP];

    if (tid < NEXP) s_lcnt[tid] = 0;

    for (int i = 0; i < 8; ++i) {
        const int l = w * 8 + i;
        const int t = blockIdx.x * RT_PB + l;

        const float* xr = x + (size_t)t * DIM;
        float4 xs[4];
#pragma unroll
        for (int j = 0; j < 4; ++j)
            xs[j] = *reinterpret_cast<const float4*>(xr + (j * 64 + lane) * 4);

        float acc[NEXP];
#pragma unroll
        for (int e = 0; e < NEXP; ++e) {
            const float* gr = gw + e * DIM;
            float s = 0.f;
#pragma unroll
            for (int j = 0; j < 4; ++j) {
                float4 g = *reinterpret_cast<const float4*>(gr + (j * 64 + lane) * 4);
                s += xs[j].x * g.x + xs[j].y * g.y + xs[j].z * g.z + xs[j].w * g.w;
            }
            acc[e] = s;
        }
#pragma unroll
        for (int off = 1; off < 64; off <<= 1) {
#pragma unroll
            for (int e = 0; e < NEXP; ++e) acc[e] += __shfl_xor(acc[e], off);
        }
#pragma unroll
        for (int e = 0; e < NEXP; ++e) acc[e] += gb[e];

        // top-2, ties -> lower index (matches jax.lax.top_k)
        int i0 = 0; float v0 = acc[0];
#pragma unroll
        for (int e = 1; e < NEXP; ++e) if (acc[e] > v0) { v0 = acc[e]; i0 = e; }
        int i1 = -1; float v1 = -3.4e38f;
#pragma unroll
        for (int e = 0; e < NEXP; ++e) if (e != i0 && acc[e] > v1) { v1 = acc[e]; i1 = e; }
        float e1  = __expf(v1 - v0);
        float inv = 1.f / (1.f + e1);
        float w0 = inv, w1 = e1 * inv;

        // fused: x -> bf16, out = w0*b[i0] + w1*b[i1]
        const float* b0 = eb + i0 * DIM;
        const float* b1 = eb + i1 * DIM;
        float* orow = out + (size_t)t * DIM;
        u16*   xrow = xb  + (size_t)t * DIM;
#pragma unroll
        for (int j = 0; j < 4; ++j) {
            int c = (j * 64 + lane) * 4;
            float4 v = xs[j];
            ushort4 u;
            u.x = f2bf(v.x); u.y = f2bf(v.y); u.z = f2bf(v.z); u.w = f2bf(v.w);
            *reinterpret_cast<ushort4*>(xrow + c) = u;
            float4 f0 = *reinterpret_cast<const float4*>(b0 + c);
            float4 f1 = *reinterpret_cast<const float4*>(b1 + c);
            float4 o;
            o.x = w0 * f0.x + w1 * f1.x;
            o.y = w0 * f0.y + w1 * f1.y;
            o.z = w0 * f0.z + w1 * f1.z;
            o.w = w0 * f0.w + w1 * f1.w;
            *reinterpret_cast<float4*>(orow + c) = o;
        }
        if (lane == 0) {
            float4 lo = make_float4(acc[0], acc[1], acc[2], acc[3]);
            float4 hi = make_float4(acc[4], acc[5], acc[6], acc[7]);
            *reinterpret_cast<float4*>(logits + (size_t)t * NEXP)     = lo;
            *reinterpret_cast<float4*>(logits + (size_t)t * NEXP + 4) = hi;
            s_sel0[l] = i0; s_sel1[l] = i1;
            s_w0[l] = w0;   s_w1[l] = w1;
        }
    }
    __syncthreads();

    int i0 = 0, i1 = 0, r0 = 0, r1 = 0;
    if (tid < RT_PB) {
        i0 = s_sel0[tid]; i1 = s_sel1[tid];
        r0 = atomicAdd(&s_lcnt[i0], 1);   // LDS atomic: local rank
        r1 = atomicAdd(&s_lcnt[i1], 1);
    }
    __syncthreads();
    if (tid < NEXP)
        s_gbase[tid] = atomicAdd(&counts[tid * 16], s_lcnt[tid]);  // 64B-padded
    __syncthreads();
    if (tid < RT_PB) {
        int t  = blockIdx.x * RT_PB + tid;
        int p0 = s_gbase[i0] + r0;
        int p1 = s_gbase[i1] + r1;
        lists[i0 * T_TOK + p0]  = t;  wlists[i0 * T_TOK + p0] = s_w0[tid];
        lists[i1 * T_TOK + p1]  = t;  wlists[i1 * T_TOK + p1] = s_w1[tid];
    }
}

// grouped GEMM: per (expert, m-tile, n-tile). C[slot][n] = sum_k x[tok][k]*W[e][n][k]
// 128x128 tile, BK=64, 4 waves (2x2), 4x4 frags of 16x16x32 bf16 MFMA.
// Staging via global_load_lds width=16 (m97 structure).
#define BM 128
#define BN 128
#define BK 64
#define MT (T_TOK / BM)   // 128
#define NT (DIM / BN)     // 8

typedef __attribute__((ext_vector_type(8))) short bf16x8;
typedef __attribute__((ext_vector_type(4))) float f32x4;

#define GLOAD_LDS16(gsrc, ldst) \
    __builtin_amdgcn_global_load_lds( \
        (const __attribute__((address_space(1))) void*)(gsrc), \
        (__attribute__((address_space(3))) void*)(ldst), 16, 0, 0)

__global__ __launch_bounds__(256) void k_gemm(
    const u16* __restrict__ xb, const u16* __restrict__ wb,
    const int* __restrict__ counts, const int* __restrict__ lists,
    const float* __restrict__ wlists, float* __restrict__ out)
{
    const int bid = blockIdx.x;
    const int e   = bid >> 10;          // / (MT*NT)
    const int mt  = (bid >> 3) & 127;
    const int nt  = bid & 7;
    const int cnt = counts[e * 16];
    if (mt * BM >= cnt) return;

    __shared__ u16 ldsA[BM * BK];
    __shared__ u16 ldsB[BN * BK];

    const int tid  = threadIdx.x;
    const int lane = tid & 63;
    const int wid  = tid >> 6;
    const int wr   = wid >> 1, wc = wid & 1;

    // staging map: chunk i covers rows i*32 + (tid>>3), k-chunk (tid&7)*8.
    // LDS element offset = i*2048 + tid*8  -> linear in tid*16B, so the
    // global_load_lds dest (wave-uniform base + lane*16B) matches exactly.
    const int srow = tid >> 3;
    const int skc  = (tid & 7) * 8;
    const int listbase = e * T_TOK;

    int tokA[4];
#pragma unroll
    for (int i = 0; i < 4; ++i) {
        int slot = mt * BM + i * 32 + srow;
        int cl   = slot < cnt ? slot : cnt - 1;
        tokA[i]  = lists[listbase + cl];
    }
    const size_t wbase = (size_t)e * DIM * DIM + (size_t)(nt * BN) * DIM;

    f32x4 acc[4][4];
#pragma unroll
    for (int mi = 0; mi < 4; ++mi)
#pragma unroll
        for (int ni = 0; ni < 4; ++ni) acc[mi][ni] = (f32x4)0.f;

    for (int k0 = 0; k0 < DIM; k0 += BK) {
#pragma unroll
        for (int i = 0; i < 4; ++i) {
            const u16* srcA = xb + (size_t)tokA[i] * DIM + k0 + skc;
            GLOAD_LDS16(srcA, ldsA + i * 2048 + wid * 512);
            const u16* srcB = wb + wbase + (size_t)(i * 32 + srow) * DIM + k0 + skc;
            GLOAD_LDS16(srcB, ldsB + i * 2048 + wid * 512);
        }
        __syncthreads();   // compiler drains vmcnt before barrier
#pragma unroll
        for (int ks = 0; ks < 2; ++ks) {
            const int kof = ks * 32 + (lane >> 4) * 8;
            bf16x8 af[4], bfr[4];
#pragma unroll
            for (int mi = 0; mi < 4; ++mi)
                af[mi] = *reinterpret_cast<const bf16x8*>(ldsA + (wr * 64 + mi * 16 + (lane & 15)) * BK + kof);
#pragma unroll
            for (int ni = 0; ni < 4; ++ni)
                bfr[ni] = *reinterpret_cast<const bf16x8*>(ldsB + (wc * 64 + ni * 16 + (lane & 15)) * BK + kof);
#pragma unroll
            for (int mi = 0; mi < 4; ++mi)
#pragma unroll
                for (int ni = 0; ni < 4; ++ni)
                    acc[mi][ni] = __builtin_amdgcn_mfma_f32_16x16x32_bf16(af[mi], bfr[ni], acc[mi][ni], 0, 0, 0);
        }
        __syncthreads();
    }

    // epilogue: C/D layout col=lane&15, row=(lane>>4)*4+reg  [m89-verified]
    const int rbase = (lane >> 4) * 4;
    const int cbase = nt * BN + wc * 64 + (lane & 15);
#pragma unroll
    for (int mi = 0; mi < 4; ++mi) {
#pragma unroll
        for (int r = 0; r < 4; ++r) {
            int slot = mt * BM + wr * 64 + mi * 16 + rbase + r;
            if (slot < cnt) {
                int   tok = lists[listbase + slot];
                float wgt = wlists[listbase + slot];
                float* orow = out + (size_t)tok * DIM + cbase;
#pragma unroll
                for (int ni = 0; ni < 4; ++ni)
                    atomicAdd(orow + ni * 16, acc[mi][ni][r] * wgt);
            }
        }
    }
}

extern "C" void kernel_launch(void* const* d_in, const int* in_sizes, int n_in,
                              void* d_out, int out_size, void* d_ws, size_t ws_size,
                              hipStream_t stream) {
    const float* x  = (const float*)d_in[0];
    const float* gw = (const float*)d_in[1];
    const float* gb = (const float*)d_in[2];
    const float* ew = (const float*)d_in[3];
    const float* eb = (const float*)d_in[4];

    float* out    = (float*)d_out;
    float* logits = out + (size_t)T_TOK * DIM;

    char* ws      = (char*)d_ws;
    u16*  xb      = (u16*)(ws + XB_OFF);
    u16*  wb      = (u16*)(ws + WB_OFF);
    int*  counts  = (int*)(ws + CNT_OFF);
    int*  lists   = (int*)(ws + LIST_OFF);
    float* wlists = (float*)(ws + WLIST_OFF);

    k_zero<<<1, 128, 0, stream>>>(counts);
    k_cvt<<<(NEXP * DIM * DIM / 4 + 255) / 256, 256, 0, stream>>>(ew, wb, NEXP * DIM * DIM / 4);
    k_router<<<T_TOK / RT_PB, 256, 0, stream>>>(x, gw, gb, eb, out, logits, xb, counts, lists, wlists);
    k_gemm<<<NEXP * MT * NT, 256, 0, stream>>>(xb, wb, counts, lists, wlists, out);
}